// Round 1
// baseline (175.154 us; speedup 1.0000x reference)
//
#include <hip/hip_runtime.h>
#include <hip/hip_bf16.h>
#include <math.h>

#define NA 250000
#define NG 64
#define NP 4096

// ---------- shared math helpers ----------

// IoU must be bitwise identical between pass1 (per-GT max) and pass2
// (force test `iou == best_per_gt`), so contraction is pinned off here.
static __device__ __forceinline__ float iou_one(
    float gx0, float gy0, float gx1, float gy1, float ga,
    float ax0, float ay0, float ax1, float ay1, float aa)
{
#pragma clang fp contract(off)
    float ltx = fmaxf(gx0, ax0);
    float lty = fmaxf(gy0, ay0);
    float rbx = fminf(gx1, ax1);
    float rby = fminf(gy1, ay1);
    float w = fmaxf(rbx - ltx, 0.0f);
    float h = fmaxf(rby - lty, 0.0f);
    float inter = w * h;
    return inter / (ga + aa - inter);
}

static __device__ __forceinline__ float smooth_l1_f(float d) {
    const float BETA = 1.0f / 9.0f;
    float ad = fabsf(d);
    return (ad < BETA) ? (0.5f * d * d / BETA) : (ad - 0.5f * BETA);
}

// ---------- kernels ----------

// ws layout: doubles[0..6) at offset 0: pos_cnt, neg_cnt, sl_pos_sum, bce_sum,
//            cls_sum, roibox_sum.  floats[64] best_per_gt at byte offset 64.
__global__ __launch_bounds__(64) void k_init(double* acc, float* best) {
    int t = threadIdx.x;
    if (t < 6) acc[t] = 0.0;
    if (t < 64) best[t] = 0.0f;
}

#define P1_APT 4
__global__ __launch_bounds__(256) void k_pass1(const float4* __restrict__ anchors,
                                               const float4* __restrict__ gt,
                                               float* __restrict__ best) {
    __shared__ float sg[5][NG];     // gx0, gy0, gx1, gy1, area
    __shared__ float swm[4][NG];    // per-wave per-gt max
    int t = threadIdx.x;
    if (t < NG) {
        float4 g = gt[t];
        sg[0][t] = g.x; sg[1][t] = g.y; sg[2][t] = g.z; sg[3][t] = g.w;
        sg[4][t] = (g.z - g.x) * (g.w - g.y);
    }
    __syncthreads();

    // load my anchors (grid-stride over k, coalesced within wave)
    float ax0[P1_APT], ay0[P1_APT], ax1[P1_APT], ay1[P1_APT], aar[P1_APT];
    int base = blockIdx.x * blockDim.x + t;
    int stride = gridDim.x * blockDim.x;
#pragma unroll
    for (int k = 0; k < P1_APT; k++) {
        int a = base + k * stride;
        float4 v = (a < NA) ? anchors[a] : make_float4(0.f, 0.f, 0.f, 0.f);
        ax0[k] = v.x; ay0[k] = v.y; ax1[k] = v.z; ay1[k] = v.w;
        aar[k] = (v.z - v.x) * (v.w - v.y);   // dummy: area 0 -> iou 0, harmless
    }

    int lane = t & 63, w = t >> 6;
    for (int g = 0; g < NG; g++) {
        float gx0 = sg[0][g], gy0 = sg[1][g], gx1 = sg[2][g], gy1 = sg[3][g], ga = sg[4][g];
        float m = 0.0f;
#pragma unroll
        for (int k = 0; k < P1_APT; k++)
            m = fmaxf(m, iou_one(gx0, gy0, gx1, gy1, ga,
                                 ax0[k], ay0[k], ax1[k], ay1[k], aar[k]));
        for (int off = 32; off > 0; off >>= 1)
            m = fmaxf(m, __shfl_down(m, off));
        if (lane == 0) swm[w][g] = m;
    }
    __syncthreads();
    if (t < NG) {
        float m = fmaxf(fmaxf(swm[0][t], swm[1][t]), fmaxf(swm[2][t], swm[3][t]));
        // IoU >= 0: int-bit compare == float compare
        atomicMax((int*)&best[t], __float_as_int(m));
    }
}

__global__ __launch_bounds__(256) void k_pass2(const float4* __restrict__ anchors,
                                               const float4* __restrict__ gt,
                                               const float* __restrict__ gscore,
                                               const int* __restrict__ gconf,
                                               const float* __restrict__ best,
                                               const float* __restrict__ objness,
                                               const float4* __restrict__ pdel,
                                               double* __restrict__ acc) {
    __shared__ float sg[7][NG];   // x0,y0,x1,y1,area,best,score
    __shared__ int sconf[NG];
    __shared__ float rbuf[4][4];
    int t = threadIdx.x;
    if (t < NG) {
        float4 g = gt[t];
        sg[0][t] = g.x; sg[1][t] = g.y; sg[2][t] = g.z; sg[3][t] = g.w;
        sg[4][t] = (g.z - g.x) * (g.w - g.y);
        sg[5][t] = best[t];
        sg[6][t] = gscore[t];
        sconf[t] = gconf[t];
    }
    __syncthreads();

    int a = blockIdx.x * 256 + t;
    float posf = 0.f, negf = 0.f, slpos = 0.f, bces = 0.f;
    if (a < NA) {
        float4 av = anchors[a];
        float aarea = (av.z - av.x) * (av.w - av.y);
        float maxv = -1.0f;
        int arg = 0;
        bool force = false;
        for (int g = 0; g < NG; g++) {
            float v = iou_one(sg[0][g], sg[1][g], sg[2][g], sg[3][g], sg[4][g],
                              av.x, av.y, av.z, av.w, aarea);
            if (v > maxv) { maxv = v; arg = g; }   // first-max tie-break == jnp.argmax
            force = force || (v == sg[5][g]);
        }
        int matched = (maxv < 0.3f) ? -1 : ((maxv < 0.7f) ? -2 : arg);
        if (force) matched = arg;
        int cl = matched < 0 ? 0 : matched;

        float label = (matched >= 0) ? 1.0f : 0.0f;
        label = fminf(label, sg[6][cl]);
        if (matched == -1) label = 0.0f;
        if (matched == -2) label = -1.0f;
        if (sconf[cl] == 0 && matched >= 0) label = -1.0f;

        bool pos = (label >= 1.0f);
        bool neg = (label == 0.0f);
        bool sel = pos || neg;

        // encode_boxes(gt[cl], anchor)
        float aw = av.z - av.x, ah = av.w - av.y;
        float acx = av.x + 0.5f * aw, acy = av.y + 0.5f * ah;
        float gx0 = sg[0][cl], gy0 = sg[1][cl], gx1 = sg[2][cl], gy1 = sg[3][cl];
        float gw = gx1 - gx0, gh = gy1 - gy0;
        float gcx = gx0 + 0.5f * gw, gcy = gy0 + 0.5f * gh;
        float t0 = (gcx - acx) / aw;
        float t1 = (gcy - acy) / ah;
        float t2 = logf(gw / aw);
        float t3 = logf(gh / ah);

        float4 pd = pdel[a];
        float sl = smooth_l1_f(pd.x - t0) + smooth_l1_f(pd.y - t1) +
                   smooth_l1_f(pd.z - t2) + smooth_l1_f(pd.w - t3);

        float x = objness[a];
        float y = sel ? fminf(fmaxf(label, 0.0f), 1.0f) : 0.0f;
        float bce = fmaxf(x, 0.0f) - x * y + log1pf(expf(-fabsf(x)));

        posf = pos ? 1.0f : 0.0f;
        negf = neg ? 1.0f : 0.0f;
        slpos = pos ? sl : 0.0f;
        bces = sel ? bce : 0.0f;
    }

    int lane = t & 63, w = t >> 6;
    for (int off = 32; off > 0; off >>= 1) {
        posf  += __shfl_down(posf, off);
        negf  += __shfl_down(negf, off);
        slpos += __shfl_down(slpos, off);
        bces  += __shfl_down(bces, off);
    }
    if (lane == 0) { rbuf[w][0] = posf; rbuf[w][1] = negf; rbuf[w][2] = slpos; rbuf[w][3] = bces; }
    __syncthreads();
    if (t == 0) {
        float s0 = 0.f, s1 = 0.f, s2 = 0.f, s3 = 0.f;
        for (int i = 0; i < 4; i++) { s0 += rbuf[i][0]; s1 += rbuf[i][1]; s2 += rbuf[i][2]; s3 += rbuf[i][3]; }
        atomicAdd(&acc[0], (double)s0);
        atomicAdd(&acc[1], (double)s1);
        atomicAdd(&acc[2], (double)s2);
        atomicAdd(&acc[3], (double)s3);
    }
}

__global__ __launch_bounds__(256) void k_roi(const float* __restrict__ logits,
                                             const float* __restrict__ breg,
                                             const int* __restrict__ rlab,
                                             const float4* __restrict__ rtgt,
                                             const float* __restrict__ rsc,
                                             double* __restrict__ acc) {
    __shared__ float rbuf[4][2];
    int t = threadIdx.x;
    int p = blockIdx.x * 256 + t;
    float clsl = 0.f, boxl = 0.f;
    if (p < NP) {
        float l0 = logits[2 * p], l1 = logits[2 * p + 1];
        float m = fmaxf(l0, l1);
        float lse = m + logf(expf(l0 - m) + expf(l1 - m));   // jax.nn.log_softmax
        float s = rsc[p];
        clsl = -((1.0f - s) * (l0 - lse) + s * (l1 - lse));

        int lbl = rlab[p];
        int cl = lbl < 0 ? 0 : lbl;
        const float* b = breg + 8 * p + 4 * cl;
        float4 tg = rtgt[p];
        float sl = smooth_l1_f(b[0] - tg.x) + smooth_l1_f(b[1] - tg.y) +
                   smooth_l1_f(b[2] - tg.z) + smooth_l1_f(b[3] - tg.w);
        boxl = (lbl > 0) ? sl : 0.0f;
    }
    int lane = t & 63, w = t >> 6;
    for (int off = 32; off > 0; off >>= 1) {
        clsl += __shfl_down(clsl, off);
        boxl += __shfl_down(boxl, off);
    }
    if (lane == 0) { rbuf[w][0] = clsl; rbuf[w][1] = boxl; }
    __syncthreads();
    if (t == 0) {
        float s0 = 0.f, s1 = 0.f;
        for (int i = 0; i < 4; i++) { s0 += rbuf[i][0]; s1 += rbuf[i][1]; }
        atomicAdd(&acc[4], (double)s0);
        atomicAdd(&acc[5], (double)s1);
    }
}

__global__ __launch_bounds__(64) void k_fin(const double* __restrict__ acc,
                                            float* __restrict__ out) {
    if (threadIdx.x == 0) {
        double n = acc[0] + acc[1];
        out[0] = (float)(acc[3] / n);          // objectness_loss
        out[1] = (float)(acc[2] / n);          // rpn_box_loss
        out[2] = (float)(acc[4] / (double)NP); // classification_loss
        out[3] = (float)(acc[5] / (double)NP); // roi_box_loss
    }
}

extern "C" void kernel_launch(void* const* d_in, const int* in_sizes, int n_in,
                              void* d_out, int out_size, void* d_ws, size_t ws_size,
                              hipStream_t stream) {
    const float4* anchors = (const float4*)d_in[0];
    const float4* gt      = (const float4*)d_in[1];
    const float*  gscore  = (const float*)d_in[2];
    const int*    gconf   = (const int*)d_in[3];
    const float*  objness = (const float*)d_in[4];
    const float4* pdel    = (const float4*)d_in[5];
    const float*  clog    = (const float*)d_in[6];
    const float*  breg    = (const float*)d_in[7];
    const int*    rlab    = (const int*)d_in[8];
    const float4* rtgt    = (const float4*)d_in[9];
    const float*  rsc     = (const float*)d_in[10];

    double* acc = (double*)d_ws;
    float* best = (float*)((char*)d_ws + 64);
    float* out = (float*)d_out;

    k_init<<<1, 64, 0, stream>>>(acc, best);
    k_pass1<<<256, 256, 0, stream>>>(anchors, gt, best);
    k_pass2<<<(NA + 255) / 256, 256, 0, stream>>>(anchors, gt, gscore, gconf, best,
                                                  objness, pdel, acc);
    k_roi<<<NP / 256, 256, 0, stream>>>(clog, breg, rlab, rtgt, rsc, acc);
    k_fin<<<1, 64, 0, stream>>>(acc, out);
}

// Round 2
// 165.156 us; speedup vs baseline: 1.0605x; 1.0605x over previous
//
#include <hip/hip_runtime.h>
#include <hip/hip_bf16.h>
#include <math.h>

#define NA 250000
#define NG 64
#define NP 4096

#define P1_APT 16
#define P1_XBLK ((NA + 256 * P1_APT - 1) / (256 * P1_APT))   // 62
#define P2_ABLK ((NA + 255) / 256)                            // 977
#define ROI_BLK (NP / 256)                                    // 16

// ---------- shared math helpers ----------

// IoU must be bitwise identical between pass1 (per-GT max) and pass2
// (force test `iou == best_per_gt`): contraction pinned off, and the
// division is a deterministic v_rcp_f32 + mul in BOTH passes.
static __device__ __forceinline__ float iou_one(
    float gx0, float gy0, float gx1, float gy1, float ga,
    float ax0, float ay0, float ax1, float ay1, float aa)
{
#pragma clang fp contract(off)
    float ltx = fmaxf(gx0, ax0);
    float lty = fmaxf(gy0, ay0);
    float rbx = fminf(gx1, ax1);
    float rby = fminf(gy1, ay1);
    float w = fmaxf(rbx - ltx, 0.0f);
    float h = fmaxf(rby - lty, 0.0f);
    float inter = w * h;
    float uni = ga + aa - inter;
    return inter * __builtin_amdgcn_rcpf(uni);   // uni > 0 always (areas > 0)
}

static __device__ __forceinline__ float smooth_l1_f(float d) {
    const float BETA = 1.0f / 9.0f;
    float ad = fabsf(d);
    return (ad < BETA) ? (0.5f * d * d / BETA) : (ad - 0.5f * BETA);
}

// ---------- kernels ----------

// ws layout: doubles[0..6): pos_cnt, neg_cnt, sl_pos_sum, bce_sum, cls_sum,
//            roibox_sum.  floats[64] best_per_gt at byte offset 64.
__global__ __launch_bounds__(64) void k_init(double* acc, float* best) {
    int t = threadIdx.x;
    if (t < 6) acc[t] = 0.0;
    if (t < 64) best[t] = 0.0f;
}

// Transposed pass1: blockIdx.y = GT index (uniform -> s_load), blockIdx.x
// tiles anchors. 16 anchors/thread, 4 independent max accumulators, one
// shuffle-reduce per thread, one atomicMax per block.
__global__ __launch_bounds__(256) void k_pass1(const float4* __restrict__ anchors,
                                               const float4* __restrict__ gt,
                                               float* __restrict__ best) {
    __shared__ float swm[4];
    int t = threadIdx.x;
    int g = blockIdx.y;
    float4 gb = gt[g];                                 // uniform address
    float ga = (gb.z - gb.x) * (gb.w - gb.y);

    float m[4] = {0.f, 0.f, 0.f, 0.f};
    int base = blockIdx.x * (256 * P1_APT) + t;
#pragma unroll
    for (int k = 0; k < P1_APT; k++) {
        int a = base + k * 256;
        float4 v = (a < NA) ? anchors[a] : make_float4(0.f, 0.f, 0.f, 0.f);
        float aa = (v.z - v.x) * (v.w - v.y);          // area 0 -> iou 0, harmless
        m[k & 3] = fmaxf(m[k & 3], iou_one(gb.x, gb.y, gb.z, gb.w, ga,
                                           v.x, v.y, v.z, v.w, aa));
    }
    float mm = fmaxf(fmaxf(m[0], m[1]), fmaxf(m[2], m[3]));
    for (int off = 32; off > 0; off >>= 1)
        mm = fmaxf(mm, __shfl_down(mm, off));
    if ((t & 63) == 0) swm[t >> 6] = mm;
    __syncthreads();
    if (t == 0) {
        mm = fmaxf(fmaxf(swm[0], swm[1]), fmaxf(swm[2], swm[3]));
        // IoU >= 0: int-bit compare == float compare
        atomicMax((int*)&best[g], __float_as_int(mm));
    }
}

// Fused: blocks [0, P2_ABLK) = per-anchor matcher + RPN losses;
//        blocks [P2_ABLK, P2_ABLK+ROI_BLK) = ROI losses.
__global__ __launch_bounds__(256) void k_main(const float4* __restrict__ anchors,
                                              const float4* __restrict__ gt,
                                              const float* __restrict__ gscore,
                                              const int* __restrict__ gconf,
                                              const float* __restrict__ best,
                                              const float* __restrict__ objness,
                                              const float4* __restrict__ pdel,
                                              const float* __restrict__ logits,
                                              const float* __restrict__ breg,
                                              const int* __restrict__ rlab,
                                              const float4* __restrict__ rtgt,
                                              const float* __restrict__ rsc,
                                              double* __restrict__ acc) {
    __shared__ float4 sgA[NG];   // x0, y0, x1, y1
    __shared__ float4 sgB[NG];   // area, best, score, conf(as float)
    __shared__ float rbuf[4][4];
    int t = threadIdx.x;
    int lane = t & 63, w = t >> 6;

    if (blockIdx.x >= P2_ABLK) {
        // ---------------- ROI part ----------------
        int p = (blockIdx.x - P2_ABLK) * 256 + t;
        float clsl = 0.f, boxl = 0.f;
        if (p < NP) {
            float l0 = logits[2 * p], l1 = logits[2 * p + 1];
            float mx = fmaxf(l0, l1);
            float lse = mx + logf(expf(l0 - mx) + expf(l1 - mx));
            float s = rsc[p];
            clsl = -((1.0f - s) * (l0 - lse) + s * (l1 - lse));

            int lbl = rlab[p];
            int cl = lbl < 0 ? 0 : lbl;
            float4 bb = *(const float4*)(breg + 8 * p + 4 * cl);  // 16B aligned
            float4 tg = rtgt[p];
            float sl = smooth_l1_f(bb.x - tg.x) + smooth_l1_f(bb.y - tg.y) +
                       smooth_l1_f(bb.z - tg.z) + smooth_l1_f(bb.w - tg.w);
            boxl = (lbl > 0) ? sl : 0.0f;
        }
        for (int off = 32; off > 0; off >>= 1) {
            clsl += __shfl_down(clsl, off);
            boxl += __shfl_down(boxl, off);
        }
        if (lane == 0) { rbuf[w][0] = clsl; rbuf[w][1] = boxl; }
        __syncthreads();
        if (t == 0) {
            float s0 = 0.f, s1 = 0.f;
            for (int i = 0; i < 4; i++) { s0 += rbuf[i][0]; s1 += rbuf[i][1]; }
            atomicAdd(&acc[4], (double)s0);
            atomicAdd(&acc[5], (double)s1);
        }
        return;
    }

    // ---------------- anchor part ----------------
    if (t < NG) {
        float4 g = gt[t];
        sgA[t] = g;
        sgB[t] = make_float4((g.z - g.x) * (g.w - g.y), best[t], gscore[t],
                             (float)gconf[t]);
    }
    __syncthreads();

    int a = blockIdx.x * 256 + t;
    float posf = 0.f, negf = 0.f, slpos = 0.f, bces = 0.f;
    if (a < NA) {
        float4 av = anchors[a];
        float aarea = (av.z - av.x) * (av.w - av.y);
        float maxv = -1.0f;
        int arg = 0;
        bool force = false;
#pragma unroll 8
        for (int g = 0; g < NG; g++) {
            float4 A = sgA[g];                 // ds_read_b128, broadcast
            float4 B = sgB[g];
            float v = iou_one(A.x, A.y, A.z, A.w, B.x,
                              av.x, av.y, av.z, av.w, aarea);
            if (v > maxv) { maxv = v; arg = g; }   // first-max == jnp.argmax
            force = force || (v == B.y);
        }
        int matched = (maxv < 0.3f) ? -1 : ((maxv < 0.7f) ? -2 : arg);
        if (force) matched = arg;
        int cl = matched < 0 ? 0 : matched;

        float4 Ac = sgA[cl];
        float4 Bc = sgB[cl];
        float label = (matched >= 0) ? 1.0f : 0.0f;
        label = fminf(label, Bc.z);
        if (matched == -1) label = 0.0f;
        if (matched == -2) label = -1.0f;
        if (Bc.w == 0.0f && matched >= 0) label = -1.0f;

        bool pos = (label >= 1.0f);
        bool neg = (label == 0.0f);
        bool sel = pos || neg;

        // encode_boxes(gt[cl], anchor)
        float aw = av.z - av.x, ah = av.w - av.y;
        float acx = av.x + 0.5f * aw, acy = av.y + 0.5f * ah;
        float gw = Ac.z - Ac.x, gh = Ac.w - Ac.y;
        float gcx = Ac.x + 0.5f * gw, gcy = Ac.y + 0.5f * gh;
        float t0 = (gcx - acx) / aw;
        float t1 = (gcy - acy) / ah;
        float t2 = logf(gw / aw);
        float t3 = logf(gh / ah);

        float4 pd = pdel[a];
        float sl = smooth_l1_f(pd.x - t0) + smooth_l1_f(pd.y - t1) +
                   smooth_l1_f(pd.z - t2) + smooth_l1_f(pd.w - t3);

        float x = objness[a];
        float y = sel ? fminf(fmaxf(label, 0.0f), 1.0f) : 0.0f;
        float bce = fmaxf(x, 0.0f) - x * y + log1pf(expf(-fabsf(x)));

        posf = pos ? 1.0f : 0.0f;
        negf = neg ? 1.0f : 0.0f;
        slpos = pos ? sl : 0.0f;
        bces = sel ? bce : 0.0f;
    }

    for (int off = 32; off > 0; off >>= 1) {
        posf  += __shfl_down(posf, off);
        negf  += __shfl_down(negf, off);
        slpos += __shfl_down(slpos, off);
        bces  += __shfl_down(bces, off);
    }
    if (lane == 0) { rbuf[w][0] = posf; rbuf[w][1] = negf; rbuf[w][2] = slpos; rbuf[w][3] = bces; }
    __syncthreads();
    if (t == 0) {
        float s0 = 0.f, s1 = 0.f, s2 = 0.f, s3 = 0.f;
        for (int i = 0; i < 4; i++) { s0 += rbuf[i][0]; s1 += rbuf[i][1]; s2 += rbuf[i][2]; s3 += rbuf[i][3]; }
        atomicAdd(&acc[0], (double)s0);
        atomicAdd(&acc[1], (double)s1);
        atomicAdd(&acc[2], (double)s2);
        atomicAdd(&acc[3], (double)s3);
    }
}

__global__ __launch_bounds__(64) void k_fin(const double* __restrict__ acc,
                                            float* __restrict__ out) {
    if (threadIdx.x == 0) {
        double n = acc[0] + acc[1];
        out[0] = (float)(acc[3] / n);          // objectness_loss
        out[1] = (float)(acc[2] / n);          // rpn_box_loss
        out[2] = (float)(acc[4] / (double)NP); // classification_loss
        out[3] = (float)(acc[5] / (double)NP); // roi_box_loss
    }
}

extern "C" void kernel_launch(void* const* d_in, const int* in_sizes, int n_in,
                              void* d_out, int out_size, void* d_ws, size_t ws_size,
                              hipStream_t stream) {
    const float4* anchors = (const float4*)d_in[0];
    const float4* gt      = (const float4*)d_in[1];
    const float*  gscore  = (const float*)d_in[2];
    const int*    gconf   = (const int*)d_in[3];
    const float*  objness = (const float*)d_in[4];
    const float4* pdel    = (const float4*)d_in[5];
    const float*  clog    = (const float*)d_in[6];
    const float*  breg    = (const float*)d_in[7];
    const int*    rlab    = (const int*)d_in[8];
    const float4* rtgt    = (const float4*)d_in[9];
    const float*  rsc     = (const float*)d_in[10];

    double* acc = (double*)d_ws;
    float* best = (float*)((char*)d_ws + 64);
    float* out = (float*)d_out;

    k_init<<<1, 64, 0, stream>>>(acc, best);
    k_pass1<<<dim3(P1_XBLK, NG), 256, 0, stream>>>(anchors, gt, best);
    k_main<<<P2_ABLK + ROI_BLK, 256, 0, stream>>>(anchors, gt, gscore, gconf, best,
                                                  objness, pdel, clog, breg, rlab,
                                                  rtgt, rsc, acc);
    k_fin<<<1, 64, 0, stream>>>(acc, out);
}

// Round 3
// 119.852 us; speedup vs baseline: 1.4614x; 1.3780x over previous
//
#include <hip/hip_runtime.h>
#include <hip/hip_bf16.h>
#include <math.h>

#define NA 250000
#define NG 64
#define NP 4096

#define SLICES 64           // anchor slices in pass1
#define SLICE_SPAN 4096     // 64*4096 = 262144 >= NA
#define GPB 4               // GTs per pass1 block
#define GGRP (NG / GPB)     // 16
#define P1_BLOCKS (SLICES * GGRP)   // 1024 (+1 gtp-writer block)
#define ABLK ((NA + 255) / 256)     // 977
#define RBLK (NP / 256)             // 16

// ws layout (floats):
//   gtp   [64*8]   @ 0      : x0,y0,x1,y1,area,best,score,conf  (32B/row)
//   wsBest[64*64]  @ 512    : [slice][g] per-(slice,g) partial max
//   wsSum [977*4]  @ 4608   : per-anchor-block partial sums (pos,neg,sl,bce)
//   wsRoi [16*2]   @ 8516   : per-roi-block partial sums (cls, box)
#define OFF_GTP  0
#define OFF_BEST 512
#define OFF_SUM  (512 + NG * SLICES)
#define OFF_ROI  (OFF_SUM + ABLK * 4)

// ---------- shared math helpers ----------

// IoU must be bitwise identical between pass1 (per-GT max) and the matcher
// (force test `iou == best_per_gt`): contraction pinned off; division is a
// deterministic v_rcp_f32 + mul in both call sites (same inlined ops).
static __device__ __forceinline__ float iou_one(
    float gx0, float gy0, float gx1, float gy1, float ga,
    float ax0, float ay0, float ax1, float ay1, float aa)
{
#pragma clang fp contract(off)
    float ltx = fmaxf(gx0, ax0);
    float lty = fmaxf(gy0, ay0);
    float rbx = fminf(gx1, ax1);
    float rby = fminf(gy1, ay1);
    float w = fmaxf(rbx - ltx, 0.0f);
    float h = fmaxf(rby - lty, 0.0f);
    float inter = w * h;
    float uni = ga + aa - inter;
    return inter * __builtin_amdgcn_rcpf(uni);   // uni > 0 always
}

static __device__ __forceinline__ float smooth_l1_f(float d) {
    const float BETA = 1.0f / 9.0f;
    float ad = fabsf(d);
    return (ad < BETA) ? (0.5f * d * d / BETA) : (ad - 0.5f * BETA);
}

// ---------- kernels ----------

// pass1: block (slice, ggrp) computes per-(slice,g) max IoU for 4 GTs over
// 4096 anchors. No atomics: result -> wsBest[slice*64+g]. Extra block 1024
// writes the packed uniform GT table gtp[] (all fields except best).
__global__ __launch_bounds__(256) void k_pass1(const float4* __restrict__ anchors,
                                               const float4* __restrict__ gt,
                                               const float* __restrict__ gscore,
                                               const int* __restrict__ gconf,
                                               float* __restrict__ ws) {
    int t = threadIdx.x;
    if (blockIdx.x == P1_BLOCKS) {
        if (t < NG) {
            float4 g = gt[t];
            float* r = ws + OFF_GTP + 8 * t;
            r[0] = g.x; r[1] = g.y; r[2] = g.z; r[3] = g.w;
            r[4] = (g.z - g.x) * (g.w - g.y);
            r[6] = gscore[t];
            r[7] = (float)gconf[t];
            // r[5] (best) written by k_mid
        }
        return;
    }
    __shared__ float swm[4][GPB];
    int slice = blockIdx.x & 63;
    int ggrp = blockIdx.x >> 6;
    int g0 = ggrp * GPB;

    float gx0[GPB], gy0[GPB], gx1[GPB], gy1[GPB], ga[GPB];
#pragma unroll
    for (int i = 0; i < GPB; i++) {
        float4 gb = gt[g0 + i];               // uniform -> s_load
        gx0[i] = gb.x; gy0[i] = gb.y; gx1[i] = gb.z; gy1[i] = gb.w;
        ga[i] = (gb.z - gb.x) * (gb.w - gb.y);
    }

    float m[GPB] = {0.f, 0.f, 0.f, 0.f};
    int base = slice * SLICE_SPAN + t;
#pragma unroll 4
    for (int k = 0; k < SLICE_SPAN / 256; k++) {
        int a = base + k * 256;
        float4 v = (a < NA) ? anchors[a] : make_float4(0.f, 0.f, 0.f, 0.f);
        float aa = (v.z - v.x) * (v.w - v.y);   // zero box -> iou 0, harmless
#pragma unroll
        for (int i = 0; i < GPB; i++)
            m[i] = fmaxf(m[i], iou_one(gx0[i], gy0[i], gx1[i], gy1[i], ga[i],
                                       v.x, v.y, v.z, v.w, aa));
    }
    int lane = t & 63, w = t >> 6;
#pragma unroll
    for (int i = 0; i < GPB; i++) {
        float mm = m[i];
        for (int off = 32; off > 0; off >>= 1)
            mm = fmaxf(mm, __shfl_down(mm, off));
        if (lane == 0) swm[w][i] = mm;
    }
    __syncthreads();
    if (t < GPB) {
        float mm = fmaxf(fmaxf(swm[0][t], swm[1][t]), fmaxf(swm[2][t], swm[3][t]));
        ws[OFF_BEST + slice * NG + g0 + t] = mm;   // plain store, no atomic
    }
}

// mid: reduce 64 slice-partials per GT -> gtp[g*8+5]
__global__ __launch_bounds__(64) void k_mid(float* __restrict__ ws) {
    int g = threadIdx.x;
    float mm = 0.f;
    for (int s = 0; s < SLICES; s++)          // coalesced: lane g, stride 64
        mm = fmaxf(mm, ws[OFF_BEST + s * NG + g]);
    ws[OFF_GTP + 8 * g + 5] = mm;
}

// main: blocks [0,ABLK) anchor matcher+losses (GT table via uniform s_load,
// no LDS in loop); blocks [ABLK, ABLK+RBLK) ROI losses. Partial sums to ws.
__global__ __launch_bounds__(256) void k_main(const float4* __restrict__ anchors,
                                              const float* __restrict__ objness,
                                              const float4* __restrict__ pdel,
                                              const float* __restrict__ logits,
                                              const float* __restrict__ breg,
                                              const int* __restrict__ rlab,
                                              const float4* __restrict__ rtgt,
                                              const float* __restrict__ rsc,
                                              float* __restrict__ ws) {
    __shared__ float rbuf[4][4];
    int t = threadIdx.x;
    int lane = t & 63, w = t >> 6;
    const float* __restrict__ gtp = ws + OFF_GTP;

    if (blockIdx.x >= ABLK) {
        // ---------------- ROI part ----------------
        int p = (blockIdx.x - ABLK) * 256 + t;
        float clsl = 0.f, boxl = 0.f;
        {
            float l0 = logits[2 * p], l1 = logits[2 * p + 1];
            float mx = fmaxf(l0, l1);
            float lse = mx + logf(expf(l0 - mx) + expf(l1 - mx));
            float s = rsc[p];
            clsl = -((1.0f - s) * (l0 - lse) + s * (l1 - lse));

            int lbl = rlab[p];
            int cl = lbl < 0 ? 0 : lbl;
            float4 bb = *(const float4*)(breg + 8 * p + 4 * cl);
            float4 tg = rtgt[p];
            float sl = smooth_l1_f(bb.x - tg.x) + smooth_l1_f(bb.y - tg.y) +
                       smooth_l1_f(bb.z - tg.z) + smooth_l1_f(bb.w - tg.w);
            boxl = (lbl > 0) ? sl : 0.0f;
        }
        for (int off = 32; off > 0; off >>= 1) {
            clsl += __shfl_down(clsl, off);
            boxl += __shfl_down(boxl, off);
        }
        if (lane == 0) { rbuf[w][0] = clsl; rbuf[w][1] = boxl; }
        __syncthreads();
        if (t == 0) {
            float s0 = 0.f, s1 = 0.f;
            for (int i = 0; i < 4; i++) { s0 += rbuf[i][0]; s1 += rbuf[i][1]; }
            float* r = ws + OFF_ROI + 2 * (blockIdx.x - ABLK);
            r[0] = s0; r[1] = s1;
        }
        return;
    }

    // ---------------- anchor part ----------------
    int a = blockIdx.x * 256 + t;
    float posf = 0.f, negf = 0.f, slpos = 0.f, bces = 0.f;
    if (a < NA) {
        float4 av = anchors[a];
        float aarea = (av.z - av.x) * (av.w - av.y);
        float maxv = -1.0f;
        int arg = 0;
        bool force = false;
#pragma unroll 8
        for (int g = 0; g < NG; g++) {
            const float* G = gtp + 8 * g;      // uniform index -> s_load
            float v = iou_one(G[0], G[1], G[2], G[3], G[4],
                              av.x, av.y, av.z, av.w, aarea);
            if (v > maxv) { maxv = v; arg = g; }   // first-max == jnp.argmax
            force = force || (v == G[5]);
        }
        int matched = (maxv < 0.3f) ? -1 : ((maxv < 0.7f) ? -2 : arg);
        if (force) matched = arg;
        int cl = matched < 0 ? 0 : matched;

        const float* Gc = gtp + 8 * cl;        // per-lane gather, 2KB L1-hot
        float4 Ac = *(const float4*)Gc;
        float score = Gc[6], conf = Gc[7];
        float label = (matched >= 0) ? 1.0f : 0.0f;
        label = fminf(label, score);
        if (matched == -1) label = 0.0f;
        if (matched == -2) label = -1.0f;
        if (conf == 0.0f && matched >= 0) label = -1.0f;

        bool pos = (label >= 1.0f);
        bool neg = (label == 0.0f);
        bool sel = pos || neg;

        float aw = av.z - av.x, ah = av.w - av.y;
        float acx = av.x + 0.5f * aw, acy = av.y + 0.5f * ah;
        float gw = Ac.z - Ac.x, gh = Ac.w - Ac.y;
        float gcx = Ac.x + 0.5f * gw, gcy = Ac.y + 0.5f * gh;
        float t0 = (gcx - acx) / aw;
        float t1 = (gcy - acy) / ah;
        float t2 = logf(gw / aw);
        float t3 = logf(gh / ah);

        float4 pd = pdel[a];
        float sl = smooth_l1_f(pd.x - t0) + smooth_l1_f(pd.y - t1) +
                   smooth_l1_f(pd.z - t2) + smooth_l1_f(pd.w - t3);

        float x = objness[a];
        float y = sel ? fminf(fmaxf(label, 0.0f), 1.0f) : 0.0f;
        float bce = fmaxf(x, 0.0f) - x * y + log1pf(expf(-fabsf(x)));

        posf = pos ? 1.0f : 0.0f;
        negf = neg ? 1.0f : 0.0f;
        slpos = pos ? sl : 0.0f;
        bces = sel ? bce : 0.0f;
    }

    for (int off = 32; off > 0; off >>= 1) {
        posf  += __shfl_down(posf, off);
        negf  += __shfl_down(negf, off);
        slpos += __shfl_down(slpos, off);
        bces  += __shfl_down(bces, off);
    }
    if (lane == 0) { rbuf[w][0] = posf; rbuf[w][1] = negf; rbuf[w][2] = slpos; rbuf[w][3] = bces; }
    __syncthreads();
    if (t == 0) {
        float s0 = 0.f, s1 = 0.f, s2 = 0.f, s3 = 0.f;
        for (int i = 0; i < 4; i++) { s0 += rbuf[i][0]; s1 += rbuf[i][1]; s2 += rbuf[i][2]; s3 += rbuf[i][3]; }
        float* r = ws + OFF_SUM + 4 * blockIdx.x;
        r[0] = s0; r[1] = s1; r[2] = s2; r[3] = s3;
    }
}

// fin: reduce all block partials (977x4 + 16x2) in doubles, emit 4 outputs.
__global__ __launch_bounds__(256) void k_fin(const float* __restrict__ ws,
                                             float* __restrict__ out) {
    __shared__ double sred[4][6];
    int t = threadIdx.x;
    int lane = t & 63, w = t >> 6;
    double a0 = 0, a1 = 0, a2 = 0, a3 = 0, c0 = 0, c1 = 0;
    for (int r = t; r < ABLK; r += 256) {
        const float4 v = *(const float4*)(ws + OFF_SUM + 4 * r);
        a0 += v.x; a1 += v.y; a2 += v.z; a3 += v.w;
    }
    if (t < RBLK) {
        c0 = ws[OFF_ROI + 2 * t];
        c1 = ws[OFF_ROI + 2 * t + 1];
    }
    for (int off = 32; off > 0; off >>= 1) {
        a0 += __shfl_down(a0, off);
        a1 += __shfl_down(a1, off);
        a2 += __shfl_down(a2, off);
        a3 += __shfl_down(a3, off);
        c0 += __shfl_down(c0, off);
        c1 += __shfl_down(c1, off);
    }
    if (lane == 0) {
        sred[w][0] = a0; sred[w][1] = a1; sred[w][2] = a2;
        sred[w][3] = a3; sred[w][4] = c0; sred[w][5] = c1;
    }
    __syncthreads();
    if (t == 0) {
        double s[6] = {0, 0, 0, 0, 0, 0};
        for (int i = 0; i < 4; i++)
            for (int j = 0; j < 6; j++) s[j] += sred[i][j];
        double n = s[0] + s[1];
        out[0] = (float)(s[3] / n);            // objectness_loss
        out[1] = (float)(s[2] / n);            // rpn_box_loss
        out[2] = (float)(s[4] / (double)NP);   // classification_loss
        out[3] = (float)(s[5] / (double)NP);   // roi_box_loss
    }
}

extern "C" void kernel_launch(void* const* d_in, const int* in_sizes, int n_in,
                              void* d_out, int out_size, void* d_ws, size_t ws_size,
                              hipStream_t stream) {
    const float4* anchors = (const float4*)d_in[0];
    const float4* gt      = (const float4*)d_in[1];
    const float*  gscore  = (const float*)d_in[2];
    const int*    gconf   = (const int*)d_in[3];
    const float*  objness = (const float*)d_in[4];
    const float4* pdel    = (const float4*)d_in[5];
    const float*  clog    = (const float*)d_in[6];
    const float*  breg    = (const float*)d_in[7];
    const int*    rlab    = (const int*)d_in[8];
    const float4* rtgt    = (const float4*)d_in[9];
    const float*  rsc     = (const float*)d_in[10];

    float* ws = (float*)d_ws;
    float* out = (float*)d_out;

    k_pass1<<<P1_BLOCKS + 1, 256, 0, stream>>>(anchors, gt, gscore, gconf, ws);
    k_mid<<<1, 64, 0, stream>>>(ws);
    k_main<<<ABLK + RBLK, 256, 0, stream>>>(anchors, objness, pdel, clog, breg,
                                            rlab, rtgt, rsc, ws);
    k_fin<<<1, 256, 0, stream>>>(ws, out);
}